// Round 24
// baseline (53.703 us; speedup 1.0000x reference)
//
#include <hip/hip_runtime.h>

#define HH 64
#define WW 64
#define TT 16
#define NPIX (HH * WW * TT)   // 65536
#define HALO 10               // 4 + 2*3
#define HWH  (HALO * HALO)    // 100 halo (h,w) positions
#define CH_SZ (HWH * TT)      // 1600 floats per channel
#define NCH 18                // gui(9, prescaled) + est(3) + var(3) + img(3)

// lane i <- lane i-1 within 16-lane DPP rows (row_shr:1), 0-fill at row start.
__device__ __forceinline__ float dpp_up1(float x) {
    return __int_as_float(__builtin_amdgcn_update_dpp(
        0, __float_as_int(x), 0x111, 0xF, 0xF, true));
}
// lane i <- lane i+1 within 16-lane DPP rows (row_shl:1), 0-fill at row end.
__device__ __forceinline__ float dpp_dn1(float x) {
    return __int_as_float(__builtin_amdgcn_update_dpp(
        0, __float_as_int(x), 0x101, 0xF, 0xF, true));
}

// The last untested cell: K=4 t-blocking at a LEGAL register budget.
// K=4 has only ever run spilled (1024thr -> 64-VGPR cap, R11/R13) or
// latency-starved (512thr -> 2 waves/SIMD, R12 31.7us). 768 threads =
// 12 waves/block -> 3 waves/SIMD -> VGPR cap ~170: the ~110-VGPR K=4
// body fits WITHOUT spill at >2 waves/SIMD for the first time.
// Occupancy axis is closed ({2,4,8}/SIMD -> {31.7,25.3,27.7}); this
// trades 1 wave/SIMD (4->3) for 2x per-lane ILP (12 independent pairs).
// grid 256 (1 blk/CU, LDS-enforced 115.2 KB), tile 4x4x16, all 18
// channels staged -> K-loop pure LDS+VALU; champion trims applied
// (prescaled gui, simplified membership, float4 staging).
// Lane = hw*4+tg (16 hw x 4 tg), owns t={4tg..4tg+3}; one wave covers
// the whole tile per column; 12 column-splits (r = s + 12i < 49).
// DPP garbage only at tg=0 (t0-1<0) / tg=3 (t0+4>15) == OOB-masked pairs.
__global__ __launch_bounds__(768, 3) void statdenoise_kernel(
    const float* __restrict__ img,
    const float* __restrict__ gui,
    const float* __restrict__ est,
    const float* __restrict__ var,
    float* __restrict__ out)
{
    __shared__ float smem[NCH * CH_SZ];   // 115.2 KB; aliased by reduction later

    const float SQS[9] = {0.31622776601683794f, 0.31622776601683794f, 0.31622776601683794f,
                          7.0710678118654755f,  7.0710678118654755f,  7.0710678118654755f,
                          3.1622776601683795f,  3.1622776601683795f,  3.1622776601683795f};
    const float G2 = 2.907f * 2.907f;   // gamma^2

    const int tid  = threadIdx.x;
    const int lane = tid & 63;
    const int s    = tid >> 6;      // wave id == column-split 0..11
    const int tg   = lane & 3;      // t-group 0..3
    const int hwl  = lane >> 2;     // tile pixel 0..15
    const int t0   = tg * 4;        // owns t0..t0+3
    const int h0   = (blockIdx.x >> 4) << 2;   // 16x16 tiles of 4x4
    const int w0   = (blockIdx.x & 15) << 2;

    // ---- stage all 18 channels of the 10x10x16 halo as float4s
    //      (edge-clamped; OOB pairs masked later by inb) ----
    if (tid < 400) {
        const int t   = (tid & 3) << 2;          // t-quad 0,4,8,12
        const int hwq = tid >> 2;                // 0..99
        const int hq  = (hwq * 205) >> 11;       // exact /10 for hwq<1024
        const int wq  = hwq - hq * 10;
        const int hs  = min(max(h0 - 3 + hq, 0), HH - 1);
        const int ws  = min(max(w0 - 3 + wq, 0), WW - 1);
        const int g   = (((hs << 6) + ws) << 4) + t;
        const int p   = hwq * 16 + t;
#pragma unroll
        for (int c = 0; c < 9; ++c) {
            float4 v = *(const float4*)&gui[c * NPIX + g];
            v.x *= SQS[c]; v.y *= SQS[c]; v.z *= SQS[c]; v.w *= SQS[c];
            *(float4*)&smem[c * CH_SZ + p] = v;
        }
#pragma unroll
        for (int c = 0; c < 3; ++c) {
            *(float4*)&smem[(9 + c)  * CH_SZ + p] = *(const float4*)&est[c * NPIX + g];
            *(float4*)&smem[(12 + c) * CH_SZ + p] = *(const float4*)&var[c * NPIX + g];
            *(float4*)&smem[(15 + c) * CH_SZ + p] = *(const float4*)&img[c * NPIX + g];
        }
    }
    __syncthreads();

    const int th = hwl >> 2, tw = hwl & 3;     // tile-local pixel
    const int hg = h0 + th,  wg = w0 + tw;     // global pixel

    // center values from LDS (float4 along t)
    const int rowc = (th + 3) * 10 + (tw + 3);
    const int lc = rowc * 16 + t0;
    float4 gc[9];
#pragma unroll
    for (int c = 0; c < 9; ++c) gc[c] = *(const float4*)&smem[c * CH_SZ + lc];
    float4 ec[3], vc[3];
#pragma unroll
    for (int c = 0; c < 3; ++c) {
        ec[c] = *(const float4*)&smem[(9 + c)  * CH_SZ + lc];
        vc[c] = *(const float4*)&smem[(12 + c) * CH_SZ + lc];
    }

    const bool vLo = (t0 != 0);     // pair (e=0,k=0): t0-1  (also DPP garbage mask)
    const bool vHi = (t0 != 12);    // pair (e=3,k=2): t0+4  (also DPP garbage mask)

    float acc[4][4] = {};   // per owned t: {r,g,b,wsum}

    int dh = s / 7 - 3, dw = s % 7 - 3;   // column r = s, then += 12
    for (int r = s; r < 49; r += 12) {
        // halo coords always in range: th+dh+3 in [0,9], tw+dw+3 in [0,9]
        const int lb  = (rowc + dh * 10 + dw) * 16 + t0;
        const bool inb = ((unsigned)(hg + dh) < (unsigned)HH) &
                         ((unsigned)(wg + dw) < (unsigned)WW);

        // ---- bilateral over 9 prescaled guidance channels, 12 pairs ----
        float sb[4][3] = {};
#pragma unroll
        for (int c = 0; c < 9; ++c) {
            float4 m = *(const float4*)&smem[c * CH_SZ + lb];
            float nv[6] = {dpp_up1(m.w), m.x, m.y, m.z, m.w, dpp_dn1(m.x)};
            float ce[4] = {gc[c].x, gc[c].y, gc[c].z, gc[c].w};
#pragma unroll
            for (int e = 0; e < 4; ++e) {
#pragma unroll
                for (int k = 0; k < 3; ++k) {        // neighbor t = t0+e+k-1
                    float d = ce[e] - nv[e + k];
                    sb[e][k] = fmaf(d, d, sb[e][k]);  // sig folded into inputs
                }
            }
        }

        // ---- membership (division-free Welch t-test, simplified) ----
        // mem = (d2==0) | (d2 < G2*V & vce!=0 & vnv!=0). Case-verified vs
        // reference; OOB h/w neighbors provably weight-0 -> masked by inb.
        bool mem[4][3] = {{1,1,1},{1,1,1},{1,1,1},{1,1,1}};
#pragma unroll
        for (int c = 0; c < 3; ++c) {
            float4 em = *(const float4*)&smem[(9 + c)  * CH_SZ + lb];
            float4 vm = *(const float4*)&smem[(12 + c) * CH_SZ + lb];
            float env[6] = {dpp_up1(em.w), em.x, em.y, em.z, em.w, dpp_dn1(em.x)};
            float vnv[6] = {dpp_up1(vm.w), vm.x, vm.y, vm.z, vm.w, dpp_dn1(vm.x)};
            float ece[4] = {ec[c].x, ec[c].y, ec[c].z, ec[c].w};
            float vce[4] = {vc[c].x, vc[c].y, vc[c].z, vc[c].w};
#pragma unroll
            for (int e = 0; e < 4; ++e) {
#pragma unroll
                for (int k = 0; k < 3; ++k) {
                    float d  = ece[e] - env[e + k];
                    float d2 = d * d;
                    float V  = vce[e] + vnv[e + k];
                    bool ok = (d2 == 0.f) |
                              ((d2 < G2 * V) & !((vce[e] == 0.f) | (vnv[e + k] == 0.f)));
                    mem[e][k] = mem[e][k] & ok;
                }
            }
        }

        // ---- weights ----
        float wt[4][3];
#pragma unroll
        for (int e = 0; e < 4; ++e) {
#pragma unroll
            for (int k = 0; k < 3; ++k) {
                bool ok = inb && mem[e][k];
                if (e == 0 && k == 0) ok = ok && vLo;   // t0-1
                if (e == 3 && k == 2) ok = ok && vHi;   // t0+4
                wt[e][k] = ok ? __expf(-0.5f * sb[e][k]) : 0.f;
            }
        }

        // ---- accumulate image (from LDS) ----
#pragma unroll
        for (int c = 0; c < 3; ++c) {
            float4 im = *(const float4*)&smem[(15 + c) * CH_SZ + lb];
            float iv[6] = {dpp_up1(im.w), im.x, im.y, im.z, im.w, dpp_dn1(im.x)};
#pragma unroll
            for (int e = 0; e < 4; ++e) {
                acc[e][c] = fmaf(wt[e][0], iv[e],
                            fmaf(wt[e][1], iv[e + 1],
                            fmaf(wt[e][2], iv[e + 2], acc[e][c])));
            }
        }
#pragma unroll
        for (int e = 0; e < 4; ++e)
            acc[e][3] += wt[e][0] + wt[e][1] + wt[e][2];

        dw += 12;
        while (dw > 3) { dw -= 7; ++dh; }
    }

    // ---- combine the 12 splits (alias staging LDS after all reads done) ----
    __syncthreads();
    float4* red = (float4*)smem;          // 12*64*4 float4 = 48 KB < 115.2 KB
#pragma unroll
    for (int e = 0; e < 4; ++e)
        red[(s * 64 + lane) * 4 + e] = make_float4(acc[e][0], acc[e][1], acc[e][2], acc[e][3]);
    __syncthreads();

    if (tid < 256) {
        const int hw_ = tid >> 4;           // tile pixel 0..15
        const int t_  = tid & 15;           // t 0..15
        const int tg_ = t_ >> 2, e_ = t_ & 3;
        const int li  = hw_ * 4 + tg_;      // lane that owns this (hw, t0) group
        float4 sum = make_float4(0.f, 0.f, 0.f, 0.f);
#pragma unroll
        for (int q = 0; q < 12; ++q) {
            float4 v = red[(q * 64 + li) * 4 + e_];
            sum.x += v.x; sum.y += v.y; sum.z += v.z; sum.w += v.w;
        }
        const int th_ = hw_ >> 2, tw_ = hw_ & 3;
        const int px = ((((h0 + th_) << 6) + (w0 + tw_)) << 4) + t_;
        const float inv = 1.f / sum.w;      // wsum >= 1 (center weight == 1)
        out[0 * NPIX + px] = sum.x * inv;
        out[1 * NPIX + px] = sum.y * inv;
        out[2 * NPIX + px] = sum.z * inv;
    }
}

extern "C" void kernel_launch(void* const* d_in, const int* in_sizes, int n_in,
                              void* d_out, int out_size, void* d_ws, size_t ws_size,
                              hipStream_t stream) {
    const float* img = (const float*)d_in[0];
    const float* gui = (const float*)d_in[1];
    const float* est = (const float*)d_in[2];
    const float* var = (const float*)d_in[3];
    float* out = (float*)d_out;

    dim3 grid(256);     // 16x16 tiles of 4x4x16, 1 block per CU (LDS-enforced)
    dim3 block(768);    // 12 waves = 12 column-splits; wave covers whole tile
    statdenoise_kernel<<<grid, block, 0, stream>>>(img, gui, est, var, out);
}

// Round 25
// 25.771 us; speedup vs baseline: 2.0838x; 2.0838x over previous
//
#include <hip/hip_runtime.h>

#define HH 64
#define WW 64
#define TT 16
#define NPIX (HH * WW * TT)   // 65536
#define HALO 10               // 4 + 2*3
#define HWH  (HALO * HALO)    // 100 halo (h,w) positions
#define CH_SZ (HWH * TT)      // 1600 floats per channel
#define NCH 18                // gui(9, prescaled) + est(3) + var(3) + img(3)

// lane i <- lane i-1 within 16-lane DPP rows (row_shr:1), 0-fill at row start.
__device__ __forceinline__ float dpp_up1(float x) {
    return __int_as_float(__builtin_amdgcn_update_dpp(
        0, __float_as_int(x), 0x111, 0xF, 0xF, true));
}
// lane i <- lane i+1 within 16-lane DPP rows (row_shl:1), 0-fill at row end.
__device__ __forceinline__ float dpp_dn1(float x) {
    return __int_as_float(__builtin_amdgcn_update_dpp(
        0, __float_as_int(x), 0x101, 0xF, 0xF, true));
}

// Champion body (R17/R21, 25.3us: grid 256 x block 1024, 1 blk/CU, K=2 +
// DPP, 16 waves = 2 pixel-groups x 8 column-splits, prescaled gui,
// simplified membership) with img STAGED TOO (18 ch, 115.2 KB LDS):
// R22 measured +2.5us when var's 6 loads went global (mid-chain), proving
// K-loop global latency is a real cost at 4 waves/SIMD. The champion's 3
// tail img loads/column are the last global accesses in the K-loop; this
// makes the K-loop 100% LDS+VALU and deletes the gnb clamp math. Body is
// otherwise bit-identical (K=4/ILP axis closed: spills at 768 and 1024
// thr; occupancy axis closed: {2,4,8} waves/SIMD -> {31.7, 25.3, 27.7}).
__global__ __launch_bounds__(1024, 4) void statdenoise_kernel(
    const float* __restrict__ img,
    const float* __restrict__ gui,
    const float* __restrict__ est,
    const float* __restrict__ var,
    float* __restrict__ out)
{
    __shared__ float smem[NCH * CH_SZ];   // 115.2 KB; aliased by reduction later

    const float SQS[9] = {0.31622776601683794f, 0.31622776601683794f, 0.31622776601683794f,
                          7.0710678118654755f,  7.0710678118654755f,  7.0710678118654755f,
                          3.1622776601683795f,  3.1622776601683795f,  3.1622776601683795f};
    const float G2 = 2.907f * 2.907f;   // gamma^2

    const int tid  = threadIdx.x;
    const int lane = tid & 63;
    const int sw   = tid >> 6;      // wave 0..15
    const int s7   = sw & 7;        // column-split 0..7
    const int pg   = sw >> 3;       // pixel-group 0..1
    const int tg   = lane & 7;      // t-group 0..7
    const int hwl  = lane >> 3;     // 0..7
    const int t0   = tg * 2;        // owns t0, t0+1
    const int h0   = (blockIdx.x >> 4) << 2;   // tile origin
    const int w0   = (blockIdx.x & 15) << 2;

    // ---- stage all 18 channels of the 10x10x16 halo as float4s
    //      (edge-clamped; OOB pairs masked later by inb) ----
    if (tid < 400) {
        const int t   = (tid & 3) << 2;          // t-quad 0,4,8,12
        const int hwq = tid >> 2;                // 0..99
        const int hq  = (hwq * 205) >> 11;       // exact /10 for hwq<1024
        const int wq  = hwq - hq * 10;
        const int hs  = min(max(h0 - 3 + hq, 0), HH - 1);
        const int ws  = min(max(w0 - 3 + wq, 0), WW - 1);
        const int g   = (((hs << 6) + ws) << 4) + t;
        const int p   = hwq * 16 + t;
#pragma unroll
        for (int c = 0; c < 9; ++c) {
            float4 v = *(const float4*)&gui[c * NPIX + g];
            v.x *= SQS[c]; v.y *= SQS[c]; v.z *= SQS[c]; v.w *= SQS[c];
            *(float4*)&smem[c * CH_SZ + p] = v;
        }
#pragma unroll
        for (int c = 0; c < 3; ++c) {
            *(float4*)&smem[(9 + c)  * CH_SZ + p] = *(const float4*)&est[c * NPIX + g];
            *(float4*)&smem[(12 + c) * CH_SZ + p] = *(const float4*)&var[c * NPIX + g];
            *(float4*)&smem[(15 + c) * CH_SZ + p] = *(const float4*)&img[c * NPIX + g];
        }
    }
    __syncthreads();

    const int pidx = pg * 8 + hwl;        // tile pixel 0..15
    const int th = pidx >> 2, tw = pidx & 3;
    const int hg = h0 + th,  wg = w0 + tw;

    // center values from LDS (center is inside the halo)
    const int lc = (((th + 3) * 10) + (tw + 3)) * 16 + t0;
    float2 gc[9];
#pragma unroll
    for (int c = 0; c < 9; ++c) gc[c] = *(const float2*)&smem[c * CH_SZ + lc];
    float2 ec[3], vc[3];
#pragma unroll
    for (int c = 0; c < 3; ++c) {
        ec[c] = *(const float2*)&smem[(9 + c)  * CH_SZ + lc];
        vc[c] = *(const float2*)&smem[(12 + c) * CH_SZ + lc];
    }

    const bool vLo = (t0 != 0);    // dt=-1 valid; also masks DPP boundary garbage
    const bool vHi = (t0 != 14);   // dt=+1 valid; also masks DPP boundary garbage

    float acc[2][4] = {};   // per owned t: {r,g,b,wsum}

    int dh = s7 / 7 - 3, dw = s7 % 7 - 3;   // column r = s7, then += 8
    for (int r = s7; r < 49; r += 8) {
        // halo coords are ALWAYS in range: th+dh+3 in [0,9], tw+dw+3 in [0,9]
        const int lb  = ((th + dh + 3) * 10 + (tw + dw + 3)) * 16 + t0;
        const bool inb = ((unsigned)(hg + dh) < (unsigned)HH) &
                         ((unsigned)(wg + dw) < (unsigned)WW);

        // ---- bilateral over 9 prescaled guidance channels, 6 pairs ----
        float sb[2][3] = {};
#pragma unroll
        for (int c = 0; c < 9; ++c) {
            float2 m = *(const float2*)&smem[c * CH_SZ + lb];
            float nv[4] = {dpp_up1(m.y), m.x, m.y, dpp_dn1(m.x)};   // t0-1..t0+2
#pragma unroll
            for (int e = 0; e < 2; ++e) {
                float ce = e ? gc[c].y : gc[c].x;
#pragma unroll
                for (int k = 0; k < 3; ++k) {
                    float d = ce - nv[e + k];
                    sb[e][k] = fmaf(d, d, sb[e][k]);   // sig folded into inputs
                }
            }
        }

        // ---- membership (division-free Welch t-test, simplified) ----
        // mem = (d2==0) | (d2 < G2*V & vce!=0 & vnv!=0). Case-verified vs
        // reference; OOB h/w neighbors provably weight-0 -> masked by inb.
        bool mem[2][3] = {{true, true, true}, {true, true, true}};
#pragma unroll
        for (int c = 0; c < 3; ++c) {
            float2 em = *(const float2*)&smem[(9 + c)  * CH_SZ + lb];
            float2 vm = *(const float2*)&smem[(12 + c) * CH_SZ + lb];
            float env[4] = {dpp_up1(em.y), em.x, em.y, dpp_dn1(em.x)};
            float vnv[4] = {dpp_up1(vm.y), vm.x, vm.y, dpp_dn1(vm.x)};
#pragma unroll
            for (int e = 0; e < 2; ++e) {
                float ece = e ? ec[c].y : ec[c].x;
                float vce = e ? vc[c].y : vc[c].x;
#pragma unroll
                for (int k = 0; k < 3; ++k) {
                    float d  = ece - env[e + k];
                    float d2 = d * d;
                    float V  = vce + vnv[e + k];
                    bool ok = (d2 == 0.f) |
                              ((d2 < G2 * V) & !((vce == 0.f) | (vnv[e + k] == 0.f)));
                    mem[e][k] = mem[e][k] & ok;
                }
            }
        }

        // ---- weights ----
        float wt[2][3];
#pragma unroll
        for (int e = 0; e < 2; ++e) {
#pragma unroll
            for (int k = 0; k < 3; ++k) {
                bool ok = inb && mem[e][k];
                if (e == 0 && k == 0) ok = ok && vLo;   // tt = t0-1
                if (e == 1 && k == 2) ok = ok && vHi;   // tt = t0+2
                wt[e][k] = ok ? __expf(-0.5f * sb[e][k]) : 0.f;
            }
        }

        // ---- accumulate image (from LDS — K-loop is now 100% LDS+VALU) ----
#pragma unroll
        for (int c = 0; c < 3; ++c) {
            float2 im = *(const float2*)&smem[(15 + c) * CH_SZ + lb];
            float iv[4] = {dpp_up1(im.y), im.x, im.y, dpp_dn1(im.x)};
#pragma unroll
            for (int e = 0; e < 2; ++e) {
                acc[e][c] = fmaf(wt[e][0], iv[e],
                            fmaf(wt[e][1], iv[e + 1],
                            fmaf(wt[e][2], iv[e + 2], acc[e][c])));
            }
        }
#pragma unroll
        for (int e = 0; e < 2; ++e)
            acc[e][3] += wt[e][0] + wt[e][1] + wt[e][2];

        dw += 8;
        while (dw > 3) { dw -= 7; ++dh; }
    }

    // ---- combine the 8 splits (alias staging LDS after all reads done) ----
    __syncthreads();
    float4* red = (float4*)smem;          // 2048 x float4 = 32 KB < 115.2 KB
    red[(sw * 64 + lane) * 2 + 0] = make_float4(acc[0][0], acc[0][1], acc[0][2], acc[0][3]);
    red[(sw * 64 + lane) * 2 + 1] = make_float4(acc[1][0], acc[1][1], acc[1][2], acc[1][3]);
    __syncthreads();

    if (tid < 256) {
        const int pg_ = tid >> 7, hwl_ = (tid >> 4) & 7, tg_ = (tid >> 1) & 7, e_ = tid & 1;
        float4 sum = make_float4(0.f, 0.f, 0.f, 0.f);
#pragma unroll
        for (int q = 0; q < 8; ++q) {
            const int swq = pg_ * 8 + q;
            float4 v = red[(swq * 64 + hwl_ * 8 + tg_) * 2 + e_];
            sum.x += v.x; sum.y += v.y; sum.z += v.z; sum.w += v.w;
        }
        const int pidx_ = pg_ * 8 + hwl_;
        const int th_ = pidx_ >> 2, tw_ = pidx_ & 3;
        const int px = ((((h0 + th_) << 6) + (w0 + tw_)) << 4) + tg_ * 2 + e_;
        const float inv = 1.f / sum.w;    // wsum >= 1 (center weight == 1)
        out[0 * NPIX + px] = sum.x * inv;
        out[1 * NPIX + px] = sum.y * inv;
        out[2 * NPIX + px] = sum.z * inv;
    }
}

extern "C" void kernel_launch(void* const* d_in, const int* in_sizes, int n_in,
                              void* d_out, int out_size, void* d_ws, size_t ws_size,
                              hipStream_t stream) {
    const float* img = (const float*)d_in[0];
    const float* gui = (const float*)d_in[1];
    const float* est = (const float*)d_in[2];
    const float* var = (const float*)d_in[3];
    float* out = (float*)d_out;

    dim3 grid(256);     // one 4x4x16 tile per block, 1 block per CU
    dim3 block(1024);   // 16 waves: 2 pixel-groups x 8 column-splits
    statdenoise_kernel<<<grid, block, 0, stream>>>(img, gui, est, var, out);
}